// Round 2
// baseline (637.280 us; speedup 1.0000x reference)
//
#include <hip/hip_runtime.h>

// ForgetMult: h_t = f_t*x_t + (1-f_t)*h_{t-1}, shapes (S=4096, B=16, H=512) fp32.
// Single-pass chunked scan with decoupled lookback.
// R2: barrier-free per-thread lookback (no LDS/syncthreads in the spin loop);
// statuses laid out contiguously per group so one round's 8 statuses share a
// cacheline. Record protocol unchanged from R1 (proven correct).

#define SQ      4096
#define NC4     2048            // float4 columns = 16*512/4
#define TT      16              // timesteps per chunk
#define NCHUNK  (SQ / TT)       // 256
#define GRID_N  (NCHUNK * 8)    // 2048 blocks (8 chain-groups)
#define LW      8               // lookback window

typedef unsigned long long u64;

__device__ __forceinline__ u64 pack2(float a, float b) {
  union { float f[2]; u64 u; } v; v.f[0] = a; v.f[1] = b; return v.u;
}

__global__ __launch_bounds__(256, 2)
void fm_scan(const float4* __restrict__ f4, const float4* __restrict__ x4,
             const float4* __restrict__ h04, float4* __restrict__ out4,
             int* ticket, int* status, u64* aggA, u64* aggB, u64* incl)
{
  __shared__ int s_tile;
  const int tid = threadIdx.x;
  // Ticket: blocks take work in start order -> lookback is deadlock-free
  // regardless of HW dispatch order.
  if (tid == 0) s_tile = atomicAdd(ticket, 1);
  __syncthreads();
  const int tile  = s_tile;
  const int chunk = tile >> 3;
  const int group = tile & 7;
  const int col   = (group << 8) + tid;   // float4 column in [0, 2048)
  const int tbase = chunk * TT;
  const int sbase = group << 8;           // status row: status[sbase + chunk]

  // ---- Phase 1: load tile (coalesced 16B/lane), stash in registers ----
  float4 fr[TT], xr[TT];
#pragma unroll
  for (int i = 0; i < TT; ++i) {
    const size_t idx = (size_t)(tbase + i) * NC4 + col;
    fr[i] = f4[idx];
    xr[i] = x4[idx];
  }

  float hx, hy, hz, hw;   // h at end of previous chunk (incl. h_init)
  if (chunk == 0) {
    const float4 h0 = h04[col];
    hx = h0.x; hy = h0.y; hz = h0.z; hw = h0.w;
  } else {
    // local aggregate: A = prod(1-f), B = local scan with h0=0
    float ax = 1.f, ay = 1.f, az = 1.f, aw = 1.f;
    float bx = 0.f, by = 0.f, bz = 0.f, bw = 0.f;
#pragma unroll
    for (int i = 0; i < TT; ++i) {
      const float4 ff = fr[i], xx = xr[i];
      bx = fmaf(ff.x, xx.x - bx, bx);
      by = fmaf(ff.y, xx.y - by, by);
      bz = fmaf(ff.z, xx.z - bz, bz);
      bw = fmaf(ff.w, xx.w - bw, bw);
      ax = fmaf(-ff.x, ax, ax);
      ay = fmaf(-ff.y, ay, ay);
      az = fmaf(-ff.z, az, az);
      aw = fmaf(-ff.w, aw, aw);
    }
    // publish aggregate (agent-scope atomics: visible across XCDs via LLC)
    {
      const size_t rb = (size_t)tile * 512 + (size_t)tid * 2;
      __hip_atomic_store(&aggA[rb],     pack2(ax, ay), __ATOMIC_RELAXED, __HIP_MEMORY_SCOPE_AGENT);
      __hip_atomic_store(&aggA[rb + 1], pack2(az, aw), __ATOMIC_RELAXED, __HIP_MEMORY_SCOPE_AGENT);
      __hip_atomic_store(&aggB[rb],     pack2(bx, by), __ATOMIC_RELAXED, __HIP_MEMORY_SCOPE_AGENT);
      __hip_atomic_store(&aggB[rb + 1], pack2(bz, bw), __ATOMIC_RELAXED, __HIP_MEMORY_SCOPE_AGENT);
    }
    __syncthreads();   // all waves' record stores drained (vmcnt(0) at barrier)
    if (tid == 0)
      __hip_atomic_store(&status[sbase + chunk], 1, __ATOMIC_RELEASE, __HIP_MEMORY_SCOPE_AGENT);

    // ---- Decoupled lookback: per-thread, no barriers in the loop ----
    float rAx = 1.f, rAy = 1.f, rAz = 1.f, rAw = 1.f;
    float rBx = 0.f, rBy = 0.f, rBz = 0.f, rBw = 0.f;
    int j = chunk - 1;
    for (;;) {
      int st[LW];
#pragma unroll
      for (int k = 0; k < LW; ++k) {
        const int jj = j - k;
        st[k] = (jj >= 0)
          ? __hip_atomic_load(&status[sbase + jj], __ATOMIC_RELAXED, __HIP_MEMORY_SCOPE_AGENT)
          : 0;
      }
      int stop = LW, m = LW;   // first k with status 0 / first k with status 2
#pragma unroll
      for (int k = LW - 1; k >= 0; --k) {
        if (st[k] == 0) stop = k;
        if (st[k] == 2) m = k;
      }
      const int c = stop < m ? stop : m;   // aggregates consumable this round
      const bool found = (m < stop);

      __builtin_amdgcn_fence(__ATOMIC_ACQUIRE, "agent");  // records now visible

      // issue all window loads back-to-back (independent -> one round trip)
      float4 Av[LW], Bv[LW];
#pragma unroll
      for (int k = 0; k < LW; ++k) {
        if (k < c) {
          const size_t rb = ((size_t)(((j - k) << 3) + group)) * 256 + tid;
          Av[k] = ((const float4*)aggA)[rb];
          Bv[k] = ((const float4*)aggB)[rb];
        }
      }
      float4 iv;
      if (found) {
        const size_t rb = ((size_t)(((j - m) << 3) + group)) * 256 + tid;
        iv = ((const float4*)incl)[rb];
      }
      // prepend progressively earlier records: B' = Bk*A_run + B_run; A' = Ak*A_run
#pragma unroll
      for (int k = 0; k < LW; ++k) {
        if (k < c) {
          rBx = fmaf(Bv[k].x, rAx, rBx);
          rBy = fmaf(Bv[k].y, rAy, rBy);
          rBz = fmaf(Bv[k].z, rAz, rBz);
          rBw = fmaf(Bv[k].w, rAw, rBw);
          rAx *= Av[k].x; rAy *= Av[k].y; rAz *= Av[k].z; rAw *= Av[k].w;
        }
      }
      if (found) {
        hx = fmaf(iv.x, rAx, rBx);
        hy = fmaf(iv.y, rAy, rBy);
        hz = fmaf(iv.z, rAz, rBz);
        hw = fmaf(iv.w, rAw, rBw);
        break;
      }
      j -= c;
      if (c == 0) __builtin_amdgcn_s_sleep(2);
    }
  }

  // ---- Phase 2: apply true prefix from registers ----
#pragma unroll
  for (int i = 0; i < TT; ++i) {
    const float4 ff = fr[i], xx = xr[i];
    hx = fmaf(ff.x, xx.x - hx, hx);
    hy = fmaf(ff.y, xx.y - hy, hy);
    hz = fmaf(ff.z, xx.z - hz, hz);
    hw = fmaf(ff.w, xx.w - hw, hw);
    float4 o; o.x = hx; o.y = hy; o.z = hz; o.w = hw;
    fr[i] = o;
  }

  // publish inclusive h (critical path: before the bulk out stores)
  if (chunk != NCHUNK - 1) {
    const size_t rb = (size_t)tile * 512 + (size_t)tid * 2;
    __hip_atomic_store(&incl[rb],     pack2(hx, hy), __ATOMIC_RELAXED, __HIP_MEMORY_SCOPE_AGENT);
    __hip_atomic_store(&incl[rb + 1], pack2(hz, hw), __ATOMIC_RELAXED, __HIP_MEMORY_SCOPE_AGENT);
    __syncthreads();
    if (tid == 0)
      __hip_atomic_store(&status[sbase + chunk], 2, __ATOMIC_RELEASE, __HIP_MEMORY_SCOPE_AGENT);
  }

#pragma unroll
  for (int i = 0; i < TT; ++i)
    out4[(size_t)(tbase + i) * NC4 + col] = fr[i];
}

// Fallback (only if ws_size is too small): one float4-column per thread.
__global__ void fm_naive(const float4* __restrict__ f4, const float4* __restrict__ x4,
                         const float4* __restrict__ h04, float4* __restrict__ out4)
{
  const int col = blockIdx.x * blockDim.x + threadIdx.x;
  if (col >= NC4) return;
  float4 h = h04[col];
  for (int t = 0; t < SQ; ++t) {
    const size_t idx = (size_t)t * NC4 + col;
    const float4 ff = f4[idx], xx = x4[idx];
    h.x = fmaf(ff.x, xx.x - h.x, h.x);
    h.y = fmaf(ff.y, xx.y - h.y, h.y);
    h.z = fmaf(ff.z, xx.z - h.z, h.z);
    h.w = fmaf(ff.w, xx.w - h.w, h.w);
    out4[idx] = h;
  }
}

extern "C" void kernel_launch(void* const* d_in, const int* in_sizes, int n_in,
                              void* d_out, int out_size, void* d_ws, size_t ws_size,
                              hipStream_t stream)
{
  const float4* f4  = (const float4*)d_in[0];
  const float4* x4  = (const float4*)d_in[1];
  const float4* h04 = (const float4*)d_in[2];
  float4* out4 = (float4*)d_out;

  const size_t HDR = 16384;                        // ticket + status flags
  const size_t REC = (size_t)GRID_N * 1024 * 4;    // 8 MB per record array
  const size_t need = HDR + 3 * REC;               // ~25.2 MB

  if (ws_size >= need) {
    hipMemsetAsync(d_ws, 0, HDR, stream);          // zero ticket + statuses
    int* ticket = (int*)d_ws;
    int* status = ticket + 64;                     // offset 256 B, 2048 ints
    u64* aggA = (u64*)((char*)d_ws + HDR);
    u64* aggB = (u64*)((char*)d_ws + HDR + REC);
    u64* incl = (u64*)((char*)d_ws + HDR + 2 * REC);
    fm_scan<<<GRID_N, 256, 0, stream>>>(f4, x4, h04, out4,
                                        ticket, status, aggA, aggB, incl);
  } else {
    fm_naive<<<(NC4 + 255) / 256, 256, 0, stream>>>(f4, x4, h04, out4);
  }
}

// Round 3
// 372.070 us; speedup vs baseline: 1.7128x; 1.7128x over previous
//
#include <hip/hip_runtime.h>

// ForgetMult: h_t = f_t*x_t + (1-f_t)*h_{t-1}, shapes (S=4096, B=16, H=512) fp32.
// R3: deterministic 3-kernel two-level scan (no atomics, no spinning).
//   K1: per-chunk aggregates (A = prod(1-f), B = local scan), TT=32 steps/chunk.
//   K2: serial scan over 128 chunk aggregates per scalar chain -> hprev per chunk.
//   K3: re-read f,x, apply recurrence from hprev, write out. Descending chunk
//       order so the re-read hits the LLC-resident tail of K1's streaming read.

#define SQ      4096
#define NC4     2048            // float4 columns = 16*512/4
#define NCH     8192            // scalar chains
#define TT      32              // timesteps per chunk
#define NCHUNK  (SQ / TT)       // 128
#define CB      8               // col-blocks per chunk (2048/256)
#define GRID1   (NCHUNK * CB)   // 1024 blocks for K1/K3

// ---- K1: chunk aggregates ----
__global__ __launch_bounds__(256, 4)
void fm_agg(const float4* __restrict__ f4, const float4* __restrict__ x4,
            float4* __restrict__ aggA, float4* __restrict__ aggB)
{
  const int tid   = threadIdx.x;
  const int chunk = blockIdx.x >> 3;
  const int col   = ((blockIdx.x & 7) << 8) + tid;
  const int tbase = chunk * TT;

  float ax = 1.f, ay = 1.f, az = 1.f, aw = 1.f;
  float bx = 0.f, by = 0.f, bz = 0.f, bw = 0.f;
#pragma unroll 8
  for (int i = 0; i < TT; ++i) {
    const size_t idx = (size_t)(tbase + i) * NC4 + col;
    const float4 ff = f4[idx];
    const float4 xx = x4[idx];
    bx = fmaf(ff.x, xx.x - bx, bx);
    by = fmaf(ff.y, xx.y - by, by);
    bz = fmaf(ff.z, xx.z - bz, bz);
    bw = fmaf(ff.w, xx.w - bw, bw);
    ax = fmaf(-ff.x, ax, ax);
    ay = fmaf(-ff.y, ay, ay);
    az = fmaf(-ff.z, az, az);
    aw = fmaf(-ff.w, aw, aw);
  }
  float4 A; A.x = ax; A.y = ay; A.z = az; A.w = aw;
  float4 B; B.x = bx; B.y = by; B.z = bz; B.w = bw;
  aggA[(size_t)chunk * NC4 + col] = A;
  aggB[(size_t)chunk * NC4 + col] = B;
}

// ---- K2: scan chunk aggregates per scalar chain ----
// Scalar view of aggA/aggB: [chunk][8192 chains] (float4 col layout == 4
// consecutive scalar chains). hprev[c][chain] = h entering chunk c.
__global__ __launch_bounds__(128, 8)
void fm_mid(const float* __restrict__ A, const float* __restrict__ B,
            const float* __restrict__ h0, float* __restrict__ hprev)
{
  const int chain = blockIdx.x * 128 + threadIdx.x;
  float h = h0[chain];
#pragma unroll 8
  for (int c = 0; c < NCHUNK; ++c) {
    const size_t idx = (size_t)c * NCH + chain;
    hprev[idx] = h;
    h = fmaf(A[idx], h, B[idx]);
  }
}

// ---- K3: apply recurrence from hprev ----
__global__ __launch_bounds__(256, 4)
void fm_apply(const float4* __restrict__ f4, const float4* __restrict__ x4,
              const float4* __restrict__ hprev4, float4* __restrict__ out4)
{
  const int tid   = threadIdx.x;
  const int chunk = (NCHUNK - 1) - (blockIdx.x >> 3);   // descending: LLC reuse
  const int col   = ((blockIdx.x & 7) << 8) + tid;
  const int tbase = chunk * TT;

  float4 h = hprev4[(size_t)chunk * NC4 + col];
#pragma unroll 8
  for (int i = 0; i < TT; ++i) {
    const size_t idx = (size_t)(tbase + i) * NC4 + col;
    const float4 ff = f4[idx];
    const float4 xx = x4[idx];
    h.x = fmaf(ff.x, xx.x - h.x, h.x);
    h.y = fmaf(ff.y, xx.y - h.y, h.y);
    h.z = fmaf(ff.z, xx.z - h.z, h.z);
    h.w = fmaf(ff.w, xx.w - h.w, h.w);
    out4[idx] = h;
  }
}

// Fallback (only if ws_size is too small): one float4-column per thread.
__global__ void fm_naive(const float4* __restrict__ f4, const float4* __restrict__ x4,
                         const float4* __restrict__ h04, float4* __restrict__ out4)
{
  const int col = blockIdx.x * blockDim.x + threadIdx.x;
  if (col >= NC4) return;
  float4 h = h04[col];
  for (int t = 0; t < SQ; ++t) {
    const size_t idx = (size_t)t * NC4 + col;
    const float4 ff = f4[idx], xx = x4[idx];
    h.x = fmaf(ff.x, xx.x - h.x, h.x);
    h.y = fmaf(ff.y, xx.y - h.y, h.y);
    h.z = fmaf(ff.z, xx.z - h.z, h.z);
    h.w = fmaf(ff.w, xx.w - h.w, h.w);
    out4[idx] = h;
  }
}

extern "C" void kernel_launch(void* const* d_in, const int* in_sizes, int n_in,
                              void* d_out, int out_size, void* d_ws, size_t ws_size,
                              hipStream_t stream)
{
  const float4* f4  = (const float4*)d_in[0];
  const float4* x4  = (const float4*)d_in[1];
  const float4* h04 = (const float4*)d_in[2];
  float4* out4 = (float4*)d_out;

  const size_t AGG = (size_t)NCHUNK * NC4 * 16;   // 4 MB per aggregate array
  const size_t HPV = (size_t)NCHUNK * NCH * 4;    // 4 MB hprev
  const size_t need = 2 * AGG + HPV;              // 12 MB

  if (ws_size >= need) {
    float4* aggA   = (float4*)d_ws;
    float4* aggB   = (float4*)((char*)d_ws + AGG);
    float*  hprev  = (float*)((char*)d_ws + 2 * AGG);
    fm_agg<<<GRID1, 256, 0, stream>>>(f4, x4, aggA, aggB);
    fm_mid<<<NCH / 128, 128, 0, stream>>>((const float*)aggA, (const float*)aggB,
                                          (const float*)h04, hprev);
    fm_apply<<<GRID1, 256, 0, stream>>>(f4, x4, (const float4*)hprev, out4);
  } else {
    fm_naive<<<(NC4 + 255) / 256, 256, 0, stream>>>(f4, x4, h04, out4);
  }
}